// Round 4
// baseline (180.035 us; speedup 1.0000x reference)
//
#include <hip/hip_runtime.h>

#define B_SZ   32
#define T_LEN  160000
#define NFFT   1024
#define HOP    320
#define FRAMES 501
#define NBINS  513
#define PADL   512

#define MROWS_BF  1024                    // interleaved cos/sin rows staged as bf16 (bins 0..511)
#define XP_STRIDE 164864                  // padded per-batch xp length (elements)
#define WS_XP_OFF (MROWS_BF * NFFT)       // ushort-element offset of xp region in ws
#define XP_G8_PB  (XP_STRIDE / 8)         // 20608 8-elem groups per batch

// prep-kernel block ranges
#define PB_BASIS  512                     // basis convert (131072 thr x 8 elems)
#define PB_XP     2576                    // xp convert    (659456 thr x 8 elems)
#define PB_BIN512 4012                    // bin512        (16048 waves >= 16032 dots)
#define PREP_BLOCKS (PB_BASIS + PB_XP + PB_BIN512)

// K-trim: Hann window (WIN=800) is zero outside k in [112,912) -> basis cols
// there are exactly 0.0. Cover with 32-aligned range [96,928): 26 tiles of 32.
#define KT0  96
#define NKT  26

#define LBUF 12288                        // elems per LDS buffer: A 8192 + B 4096

typedef __bf16 bf16x8  __attribute__((ext_vector_type(8)));
typedef float  floatx4 __attribute__((ext_vector_type(4)));

__device__ __forceinline__ unsigned short f2bf(float f) {
    unsigned u = __builtin_bit_cast(unsigned, f);
    u += 0x7FFFu + ((u >> 16) & 1u);      // round-to-nearest-even
    return (unsigned short)(u >> 16);
}

__device__ __forceinline__ void gl_lds16(const void* g, void* l) {
    __builtin_amdgcn_global_load_lds(
        (const __attribute__((address_space(1))) unsigned int*)g,
        (__attribute__((address_space(3))) unsigned int*)l, 16, 0, 0);
}

// ---- fused prep (verified R5): basis->bf16 | x->padded bf16 xp | bin512 fp32 ----
__global__ void stft_prep(const float* __restrict__ x,
                          const float* __restrict__ basis,
                          unsigned short* __restrict__ basisb,
                          unsigned short* __restrict__ xpb,
                          float* __restrict__ out) {
    const int blk = blockIdx.x;
    const int tid = threadIdx.x;

    if (blk < PB_BASIS) {
        const int gid = blk * 256 + tid;          // 8 elems per thread, exact cover
        const int row = gid >> 7;                 // 0..1023
        const int col = (gid & 127) * 8;
        const int j = row >> 1, c = row & 1;
        const float* src = basis + (size_t)(j + c * NBINS) * NFFT + col;
        const float4 v0 = *(const float4*)(src);
        const float4 v1 = *(const float4*)(src + 4);
        ushort4 o0, o1;
        o0.x = f2bf(v0.x); o0.y = f2bf(v0.y); o0.z = f2bf(v0.z); o0.w = f2bf(v0.w);
        o1.x = f2bf(v1.x); o1.y = f2bf(v1.y); o1.z = f2bf(v1.z); o1.w = f2bf(v1.w);
        unsigned short* d = basisb + ((size_t)row << 10) + col;
        *(ushort4*)(d)     = o0;
        *(ushort4*)(d + 4) = o1;
    } else if (blk < PB_BASIS + PB_XP) {
        const int i   = (blk - PB_BASIS) * 256 + tid;   // 0..659455, exact cover
        const int b   = i / XP_G8_PB;
        const int pos = (i - b * XP_G8_PB) * 8;         // boundaries (512,160512) are %8==0
        ushort4 o0 = {0,0,0,0}, o1 = {0,0,0,0};
        if (pos >= PADL && pos < T_LEN + PADL) {
            const float* src = x + (size_t)b * T_LEN + (pos - PADL);
            const float4 v0 = *(const float4*)(src);
            const float4 v1 = *(const float4*)(src + 4);
            o0.x = f2bf(v0.x); o0.y = f2bf(v0.y); o0.z = f2bf(v0.z); o0.w = f2bf(v0.w);
            o1.x = f2bf(v1.x); o1.y = f2bf(v1.y); o1.z = f2bf(v1.z); o1.w = f2bf(v1.w);
        }
        unsigned short* d = xpb + (size_t)b * XP_STRIDE + pos;
        *(ushort4*)(d)     = o0;
        *(ushort4*)(d + 4) = o1;
    } else {
        const int lane = tid & 63;
        const int d    = (blk - PB_BASIS - PB_XP) * 4 + (tid >> 6);  // wave-dot id
        if (d >= B_SZ * FRAMES) return;                              // wave-uniform
        const int b = d / FRAMES;
        const int f = d - b * FRAMES;
        const float* br = basis + (size_t)512 * NFFT + lane * 16;
        const float* xb = x + (size_t)b * T_LEN;
        const int base = f * HOP - PADL + lane * 16;
        float sum = 0.f;
        #pragma unroll
        for (int c = 0; c < 4; ++c) {
            const int xi = base + c * 4;
            const float4 bv = *(const float4*)(br + c * 4);
            float4 v;
            if (xi >= 0 && xi + 3 < T_LEN) {
                v = *(const float4*)(xb + xi);
            } else {
                v.x = (xi + 0 >= 0 && xi + 0 < T_LEN) ? xb[xi + 0] : 0.f;
                v.y = (xi + 1 >= 0 && xi + 1 < T_LEN) ? xb[xi + 1] : 0.f;
                v.z = (xi + 2 >= 0 && xi + 2 < T_LEN) ? xb[xi + 2] : 0.f;
                v.w = (xi + 3 >= 0 && xi + 3 < T_LEN) ? xb[xi + 3] : 0.f;
            }
            sum += bv.x * v.x + bv.y * v.y + bv.z * v.z + bv.w * v.w;
        }
        #pragma unroll
        for (int off = 32; off >= 1; off >>= 1) sum += __shfl_down(sum, off);
        if (lane == 0) {
            float2 val; val.x = sum; val.y = 0.f;
            *(float2*)(out + (((size_t)b * NBINS + 512) * FRAMES + f) * 2) = val;
        }
    }
}

// ---- MFMA GEMM v5: 256(M) x 128(F), BK=32, 8 waves (4M x 2N), 3 LDS bufs,
// 2 blocks/CU  --  now with FRAGMENT REGISTER DOUBLE-BUFFERING.
// Phase t: [ds_read frags(t+1)->NXT || issue DMA(t+3)->buf t%3] -> sched_barrier
//   -> MFMA(t) on CUR -> vmcnt(3) -> lgkmcnt(0) -> s_barrier -> rotate bufs.
// ds_reads issued in phase t complete under phase t's MFMA cluster (which uses
// regs loaded in phase t-1): LDS pipe and matrix pipe overlap instead of
// alternating (the R0-R3 serializer).
// Ledger: DMA(T) issued phase T-3; vmcnt(3) at end of phase T-2 drains it
// (only newest 3 = DMA(T+1) remain); barrier -> phase T-1 reads tile T safely.
// WAR: DMA(t+3) overwrites buf t%3, whose last reads (tile t, in phase t-1)
// were drained by phase t-1's lgkmcnt(0) before its exit barrier. Tail wraps
// stage/read garbage (valid addrs, regs never consumed). "memory" clobbers on
// the waitcnt asm pin all LDS ops within their phase; MFMA is register-only
// and may float (register deps compiler-enforced; no LDS hazard).
__launch_bounds__(512, 4)
__global__ void stft_mfma_kernel(const unsigned short* __restrict__ basisb,
                                 const unsigned short* __restrict__ xpb,
                                 float* __restrict__ out) {
    __shared__ unsigned short lds[3 * LBUF];   // 72 KB: per buf A[0..8191], B[8192..12287]

    const int tid  = threadIdx.x;
    const int lane = tid & 63;
    const int w    = tid >> 6;        // wave 0..7
    const int wm   = w & 3;           // 64-row quarter of 256
    const int wn   = w >> 2;          // 64-frame half of 128
    const int r0   = lane & 15;
    const int quad = lane >> 4;
    // swizzled 16B-slot within a 64-B row: slot = quad ^ ((row>>1)&3)
    const int ce   = (quad ^ ((r0 >> 1) & 3)) * 8;

    const int b   = blockIdx.x;                 // batch fastest -> XCD = b%8
    const int fg0 = blockIdx.y * 128;           // frame tile base (0..384)
    const int mg0 = blockIdx.z * 256;           // row tile base (0..768)
    const unsigned short* xpbb = xpb + (size_t)b * XP_STRIDE;

    // staging: A 256x32 (16KB, 2 loads/thr), B 128x32 (8KB, 1 load/thr).
    // LDS dest linear; global source column pre-swizzled (same involution as reads).
    const int i0 = tid, i1 = 512 + tid;
    const int rowA0 = i0 >> 2, rowA1 = i1 >> 2;        // 0..127, 128..255
    const int rowB  = tid >> 2;                        // 0..127
    const int csA0 = ((i0 & 3) ^ ((rowA0 >> 1) & 3)) * 8;
    const int csA1 = ((i1 & 3) ^ ((rowA1 >> 1) & 3)) * 8;
    const int csB  = ((tid & 3) ^ ((rowB >> 1) & 3)) * 8;
    const unsigned short* arow0 = basisb + ((size_t)(mg0 + rowA0) << 10) + csA0;
    const unsigned short* arow1 = basisb + ((size_t)(mg0 + rowA1) << 10) + csA1;
    const unsigned short* brow0 = xpbb + (size_t)(fg0 + rowB) * HOP + csB;

#define STAGE(kk, sto) do {                                         \
    const int ko_ = KT0 + (kk) * 32;                                \
    gl_lds16(arow0 + ko_, &lds[(sto) + i0 * 8]);                    \
    gl_lds16(arow1 + ko_, &lds[(sto) + i1 * 8]);                    \
    gl_lds16(brow0 + ko_, &lds[(sto) + 8192 + tid * 8]);            \
} while (0)

#define LDRD(FA, FB, oR_) do {                                                 \
    const unsigned short* pa_ = &lds[(oR_) + (wm * 64 + r0) * 32 + ce];        \
    const unsigned short* pb_ = &lds[(oR_) + 8192 + (wn * 64 + r0) * 32 + ce]; \
    _Pragma("unroll")                                                          \
    for (int mt = 0; mt < 4; ++mt) FA[mt] = *(const bf16x8*)(pa_ + mt * 512);  \
    _Pragma("unroll")                                                          \
    for (int nt = 0; nt < 4; ++nt) FB[nt] = *(const bf16x8*)(pb_ + nt * 512);  \
} while (0)

#define MFMA16(FA, FB) do {                                                    \
    _Pragma("unroll")                                                          \
    for (int mt = 0; mt < 4; ++mt)                                             \
        _Pragma("unroll")                                                      \
        for (int nt = 0; nt < 4; ++nt)                                         \
            acc[mt][nt] = __builtin_amdgcn_mfma_f32_16x16x32_bf16(             \
                FA[mt], FB[nt], acc[mt][nt], 0, 0, 0);                         \
} while (0)

// phase t: CUR=frags(t), NXT<-frags(t+1); stage tile t3=t+3 into oS=buf t%3
#define PH(FAc, FBc, FAn, FBn) do {                                            \
    int kk = t3; if (kk >= NKT) kk -= NKT;                                     \
    LDRD(FAn, FBn, oR);                                                        \
    STAGE(kk, oS);                                                             \
    __builtin_amdgcn_sched_barrier(0);                                         \
    __builtin_amdgcn_s_setprio(1);                                             \
    MFMA16(FAc, FBc);                                                          \
    __builtin_amdgcn_s_setprio(0);                                             \
    asm volatile("s_waitcnt vmcnt(3)" ::: "memory");                           \
    asm volatile("s_waitcnt lgkmcnt(0)" ::: "memory");                         \
    __builtin_amdgcn_s_barrier();                                              \
    const int tp_ = oS; oS = oR; oR = oT; oT = tp_;                            \
    ++t3;                                                                      \
} while (0)

    floatx4 acc[4][4] = {};
    bf16x8 fa0[4], fb0[4], fa1[4], fb1[4];

    // prologue: tiles 0,1,2 -> bufs 0,1,2; vmcnt(3) => tiles 0,1 landed (mine);
    // barrier => landed for ALL waves; preload tile-0 frags; drain before the
    // loop's first DMA (phase 0 stages tile 3 into buf 0).
    STAGE(0, 0); STAGE(1, LBUF); STAGE(2, 2 * LBUF);
    asm volatile("s_waitcnt vmcnt(3)" ::: "memory");
    __builtin_amdgcn_s_barrier();
    LDRD(fa0, fb0, 0);
    asm volatile("s_waitcnt lgkmcnt(0)" ::: "memory");
    __builtin_amdgcn_s_barrier();

    int oS = 0, oR = LBUF, oT = 2 * LBUF;
    int t3 = 3;
    #pragma unroll 1
    for (int it = 0; it < NKT / 2; ++it) {
        PH(fa0, fb0, fa1, fb1);
        PH(fa1, fb1, fa0, fb0);
    }

    // epilogue: rows are interleaved (cos,sin) pairs -> coalesced float2 stores
    const int mb = mg0 + wm * 64 + quad * 4;      // even
    const int fb = fg0 + wn * 64 + r0;
    #pragma unroll
    for (int nt = 0; nt < 4; ++nt) {
        const int f = fb + nt * 16;
        if (f >= FRAMES) continue;
        #pragma unroll
        for (int mt = 0; mt < 4; ++mt) {
            const int mrow = mb + mt * 16;
            const floatx4 v = acc[mt][nt];
            #pragma unroll
            for (int p = 0; p < 2; ++p) {
                const int bin = (mrow + 2 * p) >> 1;
                float2 val;
                val.x = v[2 * p];      // cos
                val.y = v[2 * p + 1];  // sin
                *(float2*)(out + (((size_t)b * NBINS + bin) * FRAMES + f) * 2) = val;
            }
        }
    }
    // drain wrap-around garbage LDS-DMA before the workgroup's LDS is freed
    asm volatile("s_waitcnt vmcnt(0)" ::: "memory");

#undef STAGE
#undef LDRD
#undef MFMA16
#undef PH
}

extern "C" void kernel_launch(void* const* d_in, const int* in_sizes, int n_in,
                              void* d_out, int out_size, void* d_ws, size_t ws_size,
                              hipStream_t stream) {
    const float* x     = (const float*)d_in[0];
    const float* basis = (const float*)d_in[1];
    float* out         = (float*)d_out;

    unsigned short* basis_bf = (unsigned short*)d_ws;
    unsigned short* xp_bf    = (unsigned short*)d_ws + WS_XP_OFF;

    stft_prep<<<dim3(PREP_BLOCKS), dim3(256), 0, stream>>>(x, basis, basis_bf, xp_bf, out);

    // batch fastest -> XCD = b%8 (per-XCD: full A 2MB + 4 batches' xp 1.3MB < L2).
    // 512 blocks, 72KB LDS -> 2 blocks/CU co-resident (16 waves/CU).
    dim3 grid(B_SZ, 4, 4);   // batches x 4 frame-tiles(128) x 4 row-tiles(256)
    stft_mfma_kernel<<<grid, dim3(512), 0, stream>>>(basis_bf, xp_bf, out);
}

// Round 5
// 147.227 us; speedup vs baseline: 1.2228x; 1.2228x over previous
//
#include <hip/hip_runtime.h>

#define B_SZ   32
#define T_LEN  160000
#define NFFT   1024
#define HOP    320
#define FRAMES 501
#define NBINS  513
#define PADL   512

#define MROWS_BF  1024                    // interleaved cos/sin rows staged as bf16 (bins 0..511)
#define XP_STRIDE 164864                  // padded per-batch xp length (elements)
#define WS_XP_OFF (MROWS_BF * NFFT)       // ushort-element offset of xp region in ws
#define XP_G8_PB  (XP_STRIDE / 8)         // 20608 8-elem groups per batch

// prep-kernel block ranges
#define PB_BASIS  512                     // basis convert (131072 thr x 8 elems)
#define PB_XP     2576                    // xp convert    (659456 thr x 8 elems)
#define PB_B512   256                     // bin512 v2: 32 batches x 8 groups of 64 frames
#define PREP_BLOCKS (PB_BASIS + PB_XP + PB_B512)

// K-trim: Hann window (WIN=800) is zero outside k in [112,912) -> basis cols
// there are exactly 0.0. Cover with 32-aligned range [96,928): 26 tiles of 32.
#define KT0  96
#define NKT  26

#define LBUF 12288                        // elems per LDS buffer: A 8192 + B 4096

typedef __bf16 bf16x8  __attribute__((ext_vector_type(8)));
typedef float  floatx4 __attribute__((ext_vector_type(4)));

__device__ __forceinline__ unsigned short f2bf(float f) {
    unsigned u = __builtin_bit_cast(unsigned, f);
    u += 0x7FFFu + ((u >> 16) & 1u);      // round-to-nearest-even
    return (unsigned short)(u >> 16);
}

__device__ __forceinline__ void gl_lds16(const void* g, void* l) {
    __builtin_amdgcn_global_load_lds(
        (const __attribute__((address_space(1))) unsigned int*)g,
        (__attribute__((address_space(3))) unsigned int*)l, 16, 0, 0);
}

// ---- fused prep: basis->bf16 | x->padded bf16 xp | bin512 v2 (dense blocks) ----
// bin512 v2: old version used 16048 blocks / 64K waves, each re-reading 4KB
// basis + 4KB x => ~128MB logical reads for a 21MB-compulsory job. Now: 256
// blocks (1/CU), basis row 512 (support t in [112,912)) staged once in LDS and
// broadcast-read (free); x read directly (guarded float4, L1/L2-served since
// frames overlap 512/832); 4 lanes per frame + shfl_xor reduce.
__global__ void stft_prep(const float* __restrict__ x,
                          const float* __restrict__ basis,
                          unsigned short* __restrict__ basisb,
                          unsigned short* __restrict__ xpb,
                          float* __restrict__ out) {
    __shared__ float bw[800];             // basis row 512, t in [112,912)
    const int blk = blockIdx.x;
    const int tid = threadIdx.x;

    if (blk < PB_BASIS) {
        const int gid = blk * 256 + tid;          // 8 elems per thread, exact cover
        const int row = gid >> 7;                 // 0..1023
        const int col = (gid & 127) * 8;
        const int j = row >> 1, c = row & 1;
        const float* src = basis + (size_t)(j + c * NBINS) * NFFT + col;
        const float4 v0 = *(const float4*)(src);
        const float4 v1 = *(const float4*)(src + 4);
        ushort4 o0, o1;
        o0.x = f2bf(v0.x); o0.y = f2bf(v0.y); o0.z = f2bf(v0.z); o0.w = f2bf(v0.w);
        o1.x = f2bf(v1.x); o1.y = f2bf(v1.y); o1.z = f2bf(v1.z); o1.w = f2bf(v1.w);
        unsigned short* d = basisb + ((size_t)row << 10) + col;
        *(ushort4*)(d)     = o0;
        *(ushort4*)(d + 4) = o1;
    } else if (blk < PB_BASIS + PB_XP) {
        const int i   = (blk - PB_BASIS) * 256 + tid;   // 0..659455, exact cover
        const int b   = i / XP_G8_PB;
        const int pos = (i - b * XP_G8_PB) * 8;         // boundaries (512,160512) are %8==0
        ushort4 o0 = {0,0,0,0}, o1 = {0,0,0,0};
        if (pos >= PADL && pos < T_LEN + PADL) {
            const float* src = x + (size_t)b * T_LEN + (pos - PADL);
            const float4 v0 = *(const float4*)(src);
            const float4 v1 = *(const float4*)(src + 4);
            o0.x = f2bf(v0.x); o0.y = f2bf(v0.y); o0.z = f2bf(v0.z); o0.w = f2bf(v0.w);
            o1.x = f2bf(v1.x); o1.y = f2bf(v1.y); o1.z = f2bf(v1.z); o1.w = f2bf(v1.w);
        }
        unsigned short* d = xpb + (size_t)b * XP_STRIDE + pos;
        *(ushort4*)(d)     = o0;
        *(ushort4*)(d + 4) = o1;
    } else {
        const int id = blk - PB_BASIS - PB_XP;    // 0..255
        const int b  = id >> 3;                   // batch
        const int g  = id & 7;                    // 64-frame group
        for (int i = tid; i < 800; i += 256)
            bw[i] = basis[(size_t)512 * NFFT + 112 + i];
        __syncthreads();
        const int j = tid >> 2;                   // frame within group (0..63)
        const int q = tid & 3;                    // quarter of the dot
        const int f = g * 64 + j;
        const float* xb = x + (size_t)b * T_LEN;
        // dot over t in [112,912): xi = f*HOP - PADL + 112 + q*200 + 4m
        const int xoff = f * HOP - 400 + q * 200;
        float sum = 0.f;
        #pragma unroll 5
        for (int m = 0; m < 50; ++m) {
            const int xi = xoff + m * 4;
            const float4 wv = *(const float4*)(&bw[q * 200 + m * 4]);
            float4 v;
            if (xi >= 0 && xi + 3 < T_LEN) {
                v = *(const float4*)(xb + xi);
            } else {
                v.x = (xi + 0 >= 0 && xi + 0 < T_LEN) ? xb[xi + 0] : 0.f;
                v.y = (xi + 1 >= 0 && xi + 1 < T_LEN) ? xb[xi + 1] : 0.f;
                v.z = (xi + 2 >= 0 && xi + 2 < T_LEN) ? xb[xi + 2] : 0.f;
                v.w = (xi + 3 >= 0 && xi + 3 < T_LEN) ? xb[xi + 3] : 0.f;
            }
            sum += wv.x * v.x + wv.y * v.y + wv.z * v.z + wv.w * v.w;
        }
        sum += __shfl_xor(sum, 1);
        sum += __shfl_xor(sum, 2);
        if (q == 0 && f < FRAMES) {
            float2 val; val.x = sum; val.y = 0.f;
            *(float2*)(out + (((size_t)b * NBINS + 512) * FRAMES + f) * 2) = val;
        }
    }
}

// ---- MFMA GEMM v6 (= proven v4/R3 + per-block K-start rotation).
// 256(M) x 128(F) tile, BK=32, 8 waves (4M x 2N -> 64x64/wave), 3 rotating
// LDS buffers (72KB -> 2 blocks/CU), one barrier/phase, distance-2 DMA
// prefetch, counted vmcnt(3) (never 0 in-loop), XOR-swizzled conflict-free
// LDS, K trimmed to window support (26 tiles, bit-identical).
// NEW: K-start rotated by 13 tiles for half the blocks (hash of (b>>3)^y^z)
// so the two co-resident blocks per CU sit at opposite phase positions --
// decorrelates their LDS-read bursts vs MFMA bursts. K-accumulation commutes.
__launch_bounds__(512, 4)
__global__ void stft_mfma_kernel(const unsigned short* __restrict__ basisb,
                                 const unsigned short* __restrict__ xpb,
                                 float* __restrict__ out) {
    __shared__ unsigned short lds[3 * LBUF];   // 72 KB: per buf A[0..8191], B[8192..12287]

    const int tid  = threadIdx.x;
    const int lane = tid & 63;
    const int w    = tid >> 6;        // wave 0..7
    const int wm   = w & 3;           // 64-row quarter of 256
    const int wn   = w >> 2;          // 64-frame half of 128
    const int r0   = lane & 15;
    const int quad = lane >> 4;
    // swizzled 16B-slot within a 64-B row: slot = quad ^ ((row>>1)&3)
    const int ce   = (quad ^ ((r0 >> 1) & 3)) * 8;

    const int b   = blockIdx.x;                 // batch fastest -> XCD = b%8
    const int fg0 = blockIdx.y * 128;           // frame tile base (0..384)
    const int mg0 = blockIdx.z * 256;           // row tile base (0..768)
    const unsigned short* xpbb = xpb + (size_t)b * XP_STRIDE;
    const int koff = (((b >> 3) ^ blockIdx.y ^ blockIdx.z) & 1) * 13;

    // staging: A 256x32 (16KB, 2 loads/thr), B 128x32 (8KB, 1 load/thr).
    // LDS dest linear; global source column pre-swizzled (same involution as reads).
    const int i0 = tid, i1 = 512 + tid;
    const int rowA0 = i0 >> 2, rowA1 = i1 >> 2;        // 0..127, 128..255
    const int rowB  = tid >> 2;                        // 0..127
    const int csA0 = ((i0 & 3) ^ ((rowA0 >> 1) & 3)) * 8;
    const int csA1 = ((i1 & 3) ^ ((rowA1 >> 1) & 3)) * 8;
    const int csB  = ((tid & 3) ^ ((rowB >> 1) & 3)) * 8;
    const unsigned short* arow0 = basisb + ((size_t)(mg0 + rowA0) << 10) + csA0;
    const unsigned short* arow1 = basisb + ((size_t)(mg0 + rowA1) << 10) + csA1;
    const unsigned short* brow0 = xpbb + (size_t)(fg0 + rowB) * HOP + csB;

#define STAGE(kk, sto) do {                                         \
    const int ko_ = KT0 + (kk) * 32;                                \
    gl_lds16(arow0 + ko_, &lds[(sto) + i0 * 8]);                    \
    gl_lds16(arow1 + ko_, &lds[(sto) + i1 * 8]);                    \
    gl_lds16(brow0 + ko_, &lds[(sto) + 8192 + tid * 8]);            \
} while (0)

    floatx4 acc[4][4] = {};

    // prologue: tiles koff..koff+2 -> bufs 0,1,2 (koff<=13 -> no wrap needed);
    // vmcnt(3) => my tile-koff stages landed.
    STAGE(koff, 0); STAGE(koff + 1, LBUF);
    asm volatile("s_waitcnt vmcnt(3)" ::: "memory");

    int rdo = 0, sto = 2 * LBUF;
    #pragma unroll 1
    for (int tt = 0; tt < NKT; ++tt) {
        __builtin_amdgcn_s_barrier();
        int kk = tt + koff + 2;                     // stage distance-2 ahead
        if (kk >= NKT) kk -= NKT;
        if (kk >= NKT) kk -= NKT;                   // tail wraps: staged, never read
        STAGE(kk, sto);

        bf16x8 af[4], bf[4];
        const unsigned short* pa = &lds[rdo + (wm * 64 + r0) * 32 + ce];
        const unsigned short* pb = &lds[rdo + 8192 + (wn * 64 + r0) * 32 + ce];
        #pragma unroll
        for (int mt = 0; mt < 4; ++mt) af[mt] = *(const bf16x8*)(pa + mt * 512);
        #pragma unroll
        for (int nt = 0; nt < 4; ++nt) bf[nt] = *(const bf16x8*)(pb + nt * 512);

        __builtin_amdgcn_s_setprio(1);
        #pragma unroll
        for (int mt = 0; mt < 4; ++mt)
            #pragma unroll
            for (int nt = 0; nt < 4; ++nt)
                acc[mt][nt] = __builtin_amdgcn_mfma_f32_16x16x32_bf16(
                    af[mt], bf[nt], acc[mt][nt], 0, 0, 0);
        __builtin_amdgcn_s_setprio(0);

        asm volatile("s_waitcnt vmcnt(3)" ::: "memory");
        rdo += LBUF; if (rdo == 3 * LBUF) rdo = 0;
        sto += LBUF; if (sto == 3 * LBUF) sto = 0;
    }
    // drain wrap-around garbage LDS-DMA before LDS is freed
    asm volatile("s_waitcnt vmcnt(0)" ::: "memory");

    // epilogue: rows are interleaved (cos,sin) pairs -> coalesced float2 stores
    const int mb = mg0 + wm * 64 + quad * 4;      // even
    const int fb = fg0 + wn * 64 + r0;
    #pragma unroll
    for (int nt = 0; nt < 4; ++nt) {
        const int f = fb + nt * 16;
        if (f >= FRAMES) continue;
        #pragma unroll
        for (int mt = 0; mt < 4; ++mt) {
            const int mrow = mb + mt * 16;
            const floatx4 v = acc[mt][nt];
            #pragma unroll
            for (int p = 0; p < 2; ++p) {
                const int bin = (mrow + 2 * p) >> 1;
                float2 val;
                val.x = v[2 * p];      // cos
                val.y = v[2 * p + 1];  // sin
                *(float2*)(out + (((size_t)b * NBINS + bin) * FRAMES + f) * 2) = val;
            }
        }
    }
#undef STAGE
}

extern "C" void kernel_launch(void* const* d_in, const int* in_sizes, int n_in,
                              void* d_out, int out_size, void* d_ws, size_t ws_size,
                              hipStream_t stream) {
    const float* x     = (const float*)d_in[0];
    const float* basis = (const float*)d_in[1];
    float* out         = (float*)d_out;

    unsigned short* basis_bf = (unsigned short*)d_ws;
    unsigned short* xp_bf    = (unsigned short*)d_ws + WS_XP_OFF;

    stft_prep<<<dim3(PREP_BLOCKS), dim3(256), 0, stream>>>(x, basis, basis_bf, xp_bf, out);

    // batch fastest -> XCD = b%8 (per-XCD: full A 2MB + 4 batches' xp 1.3MB < L2).
    // 512 blocks, 72KB LDS -> 2 blocks/CU co-resident (16 waves/CU).
    dim3 grid(B_SZ, 4, 4);   // batches x 4 frame-tiles(128) x 4 row-tiles(256)
    stft_mfma_kernel<<<grid, dim3(512), 0, stream>>>(basis_bf, xp_bf, out);
}

// Round 7
// 117.027 us; speedup vs baseline: 1.5384x; 1.2581x over previous
//
#include <hip/hip_runtime.h>

#define B_SZ   32
#define T_LEN  160000
#define NFFT   1024
#define HOP    320
#define FRAMES 501
#define NBINS  513
#define PADL   512

#define MROWS_BF  1024                    // interleaved cos/sin rows (bins 0..511); row 1024 = w512
#define XP_STRIDE 164864                  // padded per-batch xp length (elements)
#define WS_XP_OFF (1025 * NFFT)           // ushort-element offset of xp region in ws
#define XP_G8_PB  (XP_STRIDE / 8)         // 20608 8-elem groups per batch

// prep-kernel block ranges: [0,512) basis rows 0..1023 | 512: w512 row | xp convert
#define PB_BASIS  512
#define PB_XP     2576
#define PREP_BLOCKS (PB_BASIS + 1 + PB_XP)

// K-trim: Hann window (WIN=800) is zero outside k in [112,912) -> basis cols
// there are exactly 0.0. Cover with 32-aligned range [96,928): 26 tiles of 32.
#define KT0  96
#define NKT  26

#define LBUF 12288                        // elems per LDS buffer: A 8192 + B 4096

typedef __bf16 bf16x8  __attribute__((ext_vector_type(8)));
typedef float  floatx4 __attribute__((ext_vector_type(4)));

__device__ __forceinline__ unsigned short f2bf(float f) {
    unsigned u = __builtin_bit_cast(unsigned, f);
    u += 0x7FFFu + ((u >> 16) & 1u);      // round-to-nearest-even
    return (unsigned short)(u >> 16);
}

__device__ __forceinline__ void gl_lds16(const void* g, void* l) {
    __builtin_amdgcn_global_load_lds(
        (const __attribute__((address_space(1))) unsigned int*)g,
        (__attribute__((address_space(3))) unsigned int*)l, 16, 0, 0);
}

// ---- prep: pure-bandwidth converts only (bin512 now computed inside the GEMM) ----
__global__ void stft_prep(const float* __restrict__ x,
                          const float* __restrict__ basis,
                          unsigned short* __restrict__ basisb,
                          unsigned short* __restrict__ xpb,
                          float* __restrict__ out) {
    const int blk = blockIdx.x;
    const int tid = threadIdx.x;

    if (blk < PB_BASIS) {
        const int gid = blk * 256 + tid;          // 8 elems per thread, exact cover
        const int row = gid >> 7;                 // 0..1023
        const int col = (gid & 127) * 8;
        const int j = row >> 1, c = row & 1;
        const float* src = basis + (size_t)(j + c * NBINS) * NFFT + col;
        const float4 v0 = *(const float4*)(src);
        const float4 v1 = *(const float4*)(src + 4);
        ushort4 o0, o1;
        o0.x = f2bf(v0.x); o0.y = f2bf(v0.y); o0.z = f2bf(v0.z); o0.w = f2bf(v0.w);
        o1.x = f2bf(v1.x); o1.y = f2bf(v1.y); o1.z = f2bf(v1.z); o1.w = f2bf(v1.w);
        unsigned short* d = basisb + ((size_t)row << 10) + col;
        *(ushort4*)(d)     = o0;
        *(ushort4*)(d + 4) = o1;
    } else if (blk == PB_BASIS) {
        // w512 row: bf16 of basis row 512 (windowed cos_512); 256 thr x 4 elems
        const float4 v = *(const float4*)(basis + (size_t)512 * NFFT + tid * 4);
        ushort4 o;
        o.x = f2bf(v.x); o.y = f2bf(v.y); o.z = f2bf(v.z); o.w = f2bf(v.w);
        *(ushort4*)(basisb + ((size_t)1024 << 10) + tid * 4) = o;
    } else {
        const int i   = (blk - PB_BASIS - 1) * 256 + tid;   // 0..659455, exact cover
        const int b   = i / XP_G8_PB;
        const int pos = (i - b * XP_G8_PB) * 8;         // boundaries (512,160512) are %8==0
        ushort4 o0 = {0,0,0,0}, o1 = {0,0,0,0};
        if (pos >= PADL && pos < T_LEN + PADL) {
            const float* src = x + (size_t)b * T_LEN + (pos - PADL);
            const float4 v0 = *(const float4*)(src);
            const float4 v1 = *(const float4*)(src + 4);
            o0.x = f2bf(v0.x); o0.y = f2bf(v0.y); o0.z = f2bf(v0.z); o0.w = f2bf(v0.w);
            o1.x = f2bf(v1.x); o1.y = f2bf(v1.y); o1.z = f2bf(v1.z); o1.w = f2bf(v1.w);
        }
        unsigned short* d = xpb + (size_t)b * XP_STRIDE + pos;
        *(ushort4*)(d)     = o0;
        *(ushort4*)(d + 4) = o1;
    }
}

// ---- MFMA GEMM v7b = proven v4/R3 structure (+koff stagger) + fused bin512.
// 256(M) x 128(F) tile, BK=32, 8 waves (4M x 2N -> 64x64/wave), 3 rotating
// LDS buffers (72KB -> 2 blocks/CU), one barrier/phase, distance-2 DMA
// prefetch, counted vmcnt(3) (never 0 in-loop), XOR-swizzled conflict-free
// LDS, K trimmed to window support (26 tiles, bit-identical).
// bin512 fusion: w512 (basisb row 1024) staged once into LDS in the prologue
// (all 8 waves duplicate-DMA the same 2KB -> per-wave vmcnt stays uniform:
// prologue = 2+3+3 issues, vmcnt(3) drains w512+tile0). Per phase, wm==0
// waves of mg0==0 blocks run 4 extra MFMA with A = (r0==0 ? w512 : 0) against
// the already-loaded bf[nt] fragments (B-tiles ARE the xp frame windows).
// R6 bugfix: w512l is indexed by GLOBAL k -> slice addr needs the KT0 offset:
// w512l[KT0 + cur*32 + quad*8] (was missing KT0 -> 96-sample shift, absmax 29).
// Output row 0 (quad==0, reg 0, col=r0) -> coalesced float2 stores. sin512=0.
__launch_bounds__(512, 4)
__global__ void stft_mfma_kernel(const unsigned short* __restrict__ basisb,
                                 const unsigned short* __restrict__ xpb,
                                 float* __restrict__ out) {
    __shared__ unsigned short lds[3 * LBUF];   // 72 KB: per buf A[0..8191], B[8192..12287]
    __shared__ unsigned short w512l[1024];     // w512 row, global k in [0,1024)

    const int tid  = threadIdx.x;
    const int lane = tid & 63;
    const int w    = tid >> 6;        // wave 0..7
    const int wm   = w & 3;           // 64-row quarter of 256
    const int wn   = w >> 2;          // 64-frame half of 128
    const int r0   = lane & 15;
    const int quad = lane >> 4;
    // swizzled 16B-slot within a 64-B row: slot = quad ^ ((row>>1)&3)
    const int ce   = (quad ^ ((r0 >> 1) & 3)) * 8;

    const int b   = blockIdx.x;                 // batch fastest -> XCD = b%8
    const int fg0 = blockIdx.y * 128;           // frame tile base (0..384)
    const int mg0 = blockIdx.z * 256;           // row tile base (0..768)
    const unsigned short* xpbb = xpb + (size_t)b * XP_STRIDE;
    const int koff = (((b >> 3) ^ blockIdx.y ^ blockIdx.z) & 1) * 13;
    const bool do512 = (mg0 == 0) && (wm == 0);  // wave-uniform

    // staging: A 256x32 (16KB, 2 loads/thr), B 128x32 (8KB, 1 load/thr).
    // LDS dest linear; global source column pre-swizzled (same involution as reads).
    const int i0 = tid, i1 = 512 + tid;
    const int rowA0 = i0 >> 2, rowA1 = i1 >> 2;        // 0..127, 128..255
    const int rowB  = tid >> 2;                        // 0..127
    const int csA0 = ((i0 & 3) ^ ((rowA0 >> 1) & 3)) * 8;
    const int csA1 = ((i1 & 3) ^ ((rowA1 >> 1) & 3)) * 8;
    const int csB  = ((tid & 3) ^ ((rowB >> 1) & 3)) * 8;
    const unsigned short* arow0 = basisb + ((size_t)(mg0 + rowA0) << 10) + csA0;
    const unsigned short* arow1 = basisb + ((size_t)(mg0 + rowA1) << 10) + csA1;
    const unsigned short* brow0 = xpbb + (size_t)(fg0 + rowB) * HOP + csB;

#define STAGE(kk, sto) do {                                         \
    const int ko_ = KT0 + (kk) * 32;                                \
    gl_lds16(arow0 + ko_, &lds[(sto) + i0 * 8]);                    \
    gl_lds16(arow1 + ko_, &lds[(sto) + i1 * 8]);                    \
    gl_lds16(brow0 + ko_, &lds[(sto) + 8192 + tid * 8]);            \
} while (0)

    floatx4 acc[4][4] = {};
    floatx4 acc512[4] = {};

    // prologue: w512 (2 issues, all waves duplicate same region - benign) then
    // tiles koff,koff+1 -> bufs 0,1. vmcnt(3) => w512 + tile-koff landed (mine).
    gl_lds16(basisb + ((size_t)1024 << 10) + lane * 8, &w512l[lane * 8]);
    gl_lds16(basisb + ((size_t)1024 << 10) + 512 + lane * 8, &w512l[512 + lane * 8]);
    STAGE(koff, 0); STAGE(koff + 1, LBUF);
    asm volatile("s_waitcnt vmcnt(3)" ::: "memory");

    int rdo = 0, sto = 2 * LBUF;
    #pragma unroll 1
    for (int tt = 0; tt < NKT; ++tt) {
        __builtin_amdgcn_s_barrier();
        int kk = tt + koff + 2;                     // stage distance-2 ahead
        if (kk >= NKT) kk -= NKT;
        if (kk >= NKT) kk -= NKT;                   // tail wraps: staged, never read
        STAGE(kk, sto);

        bf16x8 af[4], bf[4];
        const unsigned short* pa = &lds[rdo + (wm * 64 + r0) * 32 + ce];
        const unsigned short* pb = &lds[rdo + 8192 + (wn * 64 + r0) * 32 + ce];
        #pragma unroll
        for (int mt = 0; mt < 4; ++mt) af[mt] = *(const bf16x8*)(pa + mt * 512);
        #pragma unroll
        for (int nt = 0; nt < 4; ++nt) bf[nt] = *(const bf16x8*)(pb + nt * 512);

        __builtin_amdgcn_s_setprio(1);
        #pragma unroll
        for (int mt = 0; mt < 4; ++mt)
            #pragma unroll
            for (int nt = 0; nt < 4; ++nt)
                acc[mt][nt] = __builtin_amdgcn_mfma_f32_16x16x32_bf16(
                    af[mt], bf[nt], acc[mt][nt], 0, 0, 0);
        __builtin_amdgcn_s_setprio(0);

        if (do512) {                                // wave-uniform branch
            int cur = tt + koff; if (cur >= NKT) cur -= NKT;
            bf16x8 aw = {};
            if (r0 == 0)                            // A row 0 = w512, rows 1..15 = 0
                aw = *(const bf16x8*)(&w512l[KT0 + cur * 32 + quad * 8]);
            #pragma unroll
            for (int nt = 0; nt < 4; ++nt)
                acc512[nt] = __builtin_amdgcn_mfma_f32_16x16x32_bf16(
                    aw, bf[nt], acc512[nt], 0, 0, 0);
        }

        asm volatile("s_waitcnt vmcnt(3)" ::: "memory");
        rdo += LBUF; if (rdo == 3 * LBUF) rdo = 0;
        sto += LBUF; if (sto == 3 * LBUF) sto = 0;
    }
    // drain wrap-around garbage LDS-DMA before LDS is freed
    asm volatile("s_waitcnt vmcnt(0)" ::: "memory");

    // epilogue: rows are interleaved (cos,sin) pairs -> coalesced float2 stores
    const int mb = mg0 + wm * 64 + quad * 4;      // even
    const int fb = fg0 + wn * 64 + r0;
    #pragma unroll
    for (int nt = 0; nt < 4; ++nt) {
        const int f = fb + nt * 16;
        if (f >= FRAMES) continue;
        #pragma unroll
        for (int mt = 0; mt < 4; ++mt) {
            const int mrow = mb + mt * 16;
            const floatx4 v = acc[mt][nt];
            #pragma unroll
            for (int p = 0; p < 2; ++p) {
                const int bin = (mrow + 2 * p) >> 1;
                float2 val;
                val.x = v[2 * p];      // cos
                val.y = v[2 * p + 1];  // sin
                *(float2*)(out + (((size_t)b * NBINS + bin) * FRAMES + f) * 2) = val;
            }
        }
    }
    // bin512: output row 0 lives in quad==0 lanes, reg 0, col=r0
    if (do512 && quad == 0) {
        #pragma unroll
        for (int nt = 0; nt < 4; ++nt) {
            const int f = fb + nt * 16;
            if (f < FRAMES) {
                float2 val; val.x = acc512[nt][0]; val.y = 0.f;
                *(float2*)(out + (((size_t)b * NBINS + 512) * FRAMES + f) * 2) = val;
            }
        }
    }
#undef STAGE
}

extern "C" void kernel_launch(void* const* d_in, const int* in_sizes, int n_in,
                              void* d_out, int out_size, void* d_ws, size_t ws_size,
                              hipStream_t stream) {
    const float* x     = (const float*)d_in[0];
    const float* basis = (const float*)d_in[1];
    float* out         = (float*)d_out;

    unsigned short* basis_bf = (unsigned short*)d_ws;
    unsigned short* xp_bf    = (unsigned short*)d_ws + WS_XP_OFF;

    stft_prep<<<dim3(PREP_BLOCKS), dim3(256), 0, stream>>>(x, basis, basis_bf, xp_bf, out);

    // batch fastest -> XCD = b%8 (per-XCD: full A 2MB + 4 batches' xp 1.3MB < L2).
    // 512 blocks, ~74KB LDS -> 2 blocks/CU co-resident (16 waves/CU).
    dim3 grid(B_SZ, 4, 4);   // batches x 4 frame-tiles(128) x 4 row-tiles(256)
    stft_mfma_kernel<<<grid, dim3(512), 0, stream>>>(basis_bf, xp_bf, out);
}